// Round 12
// baseline (385.407 us; speedup 1.0000x reference)
//
#include <hip/hip_runtime.h>
#include <hip/hip_bf16.h>
#include <math.h>

#define NHEADS 20

typedef short bf16x8 __attribute__((ext_vector_type(8)));
typedef float f32x4 __attribute__((ext_vector_type(4)));

__device__ inline float bf2f(unsigned short u) {
  union { unsigned int i; float f; } x; x.i = ((unsigned int)u) << 16; return x.f;
}
__device__ inline unsigned short f2bf(float f) {
  __hip_bfloat16 h = __float2bfloat16(f);
  union { __hip_bfloat16 h; unsigned short u; } x; x.h = h; return x.u;
}
__device__ inline unsigned int pk2(float a, float b) {
  return (unsigned int)f2bf(a) | ((unsigned int)f2bf(b) << 16);
}
__device__ inline void gload_lds16(const void* g, void* l) {
  __builtin_amdgcn_global_load_lds(
      (const __attribute__((address_space(1))) void*)g,
      (__attribute__((address_space(3))) void*)l, 16, 0, 0);
}

// ---------------- fp32 -> bf16 copy (8 elems/thread) ------------------------
__global__ __launch_bounds__(256) void f32_to_bf16_kernel(
    const float* __restrict__ in, unsigned short* __restrict__ out, int n8) {
  int idx = blockIdx.x * 256 + threadIdx.x;
  if (idx < n8) {
    float4 a = reinterpret_cast<const float4*>(in)[idx * 2];
    float4 b = reinterpret_cast<const float4*>(in)[idx * 2 + 1];
    union { unsigned short u[8]; uint4 v; } o;
    o.u[0] = f2bf(a.x); o.u[1] = f2bf(a.y); o.u[2] = f2bf(a.z); o.u[3] = f2bf(a.w);
    o.u[4] = f2bf(b.x); o.u[5] = f2bf(b.y); o.u[6] = f2bf(b.z); o.u[7] = f2bf(b.w);
    reinterpret_cast<uint4*>(out)[idx] = o.v;
  }
}

// ---------------- rope cos/sin table: cs[pos*32+fi] -------------------------
__global__ __launch_bounds__(256) void rope_table_kernel(float2* __restrict__ cs) {
  int idx = blockIdx.x * 256 + threadIdx.x;   // 2048*32
  int pos = idx >> 5, fi = idx & 31;
  float inv = exp2f(-(float)fi * 0.622861517f);   // 1e6^(-fi/32)
  float ang = (float)pos * inv;
  cs[idx] = make_float2(cosf(ang), sinf(ang));
}

// ---------------- fp32 [R,C] -> bf16 transposed [C,R] -----------------------
__global__ __launch_bounds__(256) void transpose_f32_bf16(
    const float* __restrict__ in, unsigned short* __restrict__ out, int R, int C0) {
  __shared__ float tile[32][33];
  const int tx = threadIdx.x, ty = threadIdx.y;
  const int bc = blockIdx.x * 32, br = blockIdx.y * 32;
  #pragma unroll
  for (int j = 0; j < 4; ++j)
    tile[ty + 8 * j][tx] = in[(size_t)(br + ty + 8 * j) * C0 + bc + tx];
  __syncthreads();
  #pragma unroll
  for (int j = 0; j < 4; ++j)
    out[(size_t)(bc + ty + 8 * j) * R + br + tx] = f2bf(tile[tx][ty + 8 * j]);
}

// ---------------- elementwise multi-part reduce (float4) --------------------
__global__ __launch_bounds__(256) void reduce_add_kernel(
    const float* __restrict__ in, float* __restrict__ out, int n4, int parts, size_t stride4) {
  int idx = blockIdx.x * 256 + threadIdx.x;
  if (idx < n4) {
    const float4* in4 = reinterpret_cast<const float4*>(in);
    float4 s = in4[idx];
    for (int p = 1; p < parts; ++p) {
      float4 b = in4[idx + p * stride4];
      s.x += b.x; s.y += b.y; s.z += b.z; s.w += b.w;
    }
    reinterpret_cast<float4*>(out)[idx] = s;
  }
}

// ---------------- bf16 MFMA GEMM, 2-phase dbuf ------------------------------
// MODE 0: f32 out (split-K partials if gridDim.z>1)
// MODE 2: Q-pack epilogue: rope (cs table) + write Qc fragment layout
// MODE 3: KV-pack epilogue: write Kc nope + Vc fragment layouts
template <int MODE>
__global__ __launch_bounds__(256) void gemm_mfma(
    const unsigned short* __restrict__ A, const unsigned short* __restrict__ Bt,
    void* __restrict__ Cout, void* __restrict__ Cout2, const float2* __restrict__ cs,
    int M, int N, int K, int ksize) {
  __shared__ unsigned short As[2][4096] __attribute__((aligned(16)));
  __shared__ unsigned short Bs[2][4096] __attribute__((aligned(16)));
  const int t = threadIdx.x;
  const int l = t & 63;
  const int w = t >> 6;
  const int bm = blockIdx.y * 128;
  const int bn = blockIdx.x * 128;
  const int kbase = blockIdx.z * ksize;
  const int wr = w >> 1, wc = w & 1;
  const int lr = l & 15, lk = (l >> 4) * 8;
  const int g4 = l >> 4;

  f32x4 acc[4][4];
  #pragma unroll
  for (int i = 0; i < 4; ++i)
    #pragma unroll
    for (int j = 0; j < 4; ++j) acc[i][j] = (f32x4){0.f, 0.f, 0.f, 0.f};

  int arow0 = bm + (w + 0) * 16 + lr;
  int arow1 = bm + (w + 4) * 16 + lr;
  int bcol0 = bn + (w + 0) * 16 + lr; if (bcol0 >= N) bcol0 = N - 1;
  int bcol1 = bn + (w + 4) * 16 + lr; if (bcol1 >= N) bcol1 = N - 1;
  const unsigned short* aptr0 = A + (size_t)arow0 * K + kbase + lk;
  const unsigned short* aptr1 = A + (size_t)arow1 * K + kbase + lk;
  const unsigned short* bptr0 = Bt + (size_t)bcol0 * K + kbase + lk;
  const unsigned short* bptr1 = Bt + (size_t)bcol1 * K + kbase + lk;

#define GEMM_STAGE(buf, koff)                                  \
  gload_lds16(aptr0 + (koff), &As[buf][(w + 0) * 512]);        \
  gload_lds16(aptr1 + (koff), &As[buf][(w + 4) * 512]);        \
  gload_lds16(bptr0 + (koff), &Bs[buf][(w + 0) * 512]);        \
  gload_lds16(bptr1 + (koff), &Bs[buf][(w + 4) * 512]);

  GEMM_STAGE(0, 0)
  int cur = 0;
  for (int k0 = 0; k0 < ksize; k0 += 32) {
    if (k0 + 32 < ksize) {
      GEMM_STAGE(cur ^ 1, k0 + 32)
      asm volatile("s_waitcnt vmcnt(4)" ::: "memory");
    } else {
      asm volatile("s_waitcnt vmcnt(0)" ::: "memory");
    }
    __builtin_amdgcn_s_barrier();
    bf16x8 af[4], bfr[4];
    #pragma unroll
    for (int mi = 0; mi < 4; ++mi)
      af[mi] = *reinterpret_cast<const bf16x8*>(&As[cur][(wr * 4 + mi) * 512 + l * 8]);
    #pragma unroll
    for (int nj = 0; nj < 4; ++nj)
      bfr[nj] = *reinterpret_cast<const bf16x8*>(&Bs[cur][(wc * 4 + nj) * 512 + l * 8]);
    #pragma unroll
    for (int mi = 0; mi < 4; ++mi)
      #pragma unroll
      for (int nj = 0; nj < 4; ++nj)
        acc[mi][nj] = __builtin_amdgcn_mfma_f32_16x16x32_bf16(af[mi], bfr[nj], acc[mi][nj], 0, 0, 0);
    __builtin_amdgcn_s_barrier();
    cur ^= 1;
  }
#undef GEMM_STAGE

  if constexpr (MODE == 0) {
    const bool split = (gridDim.z > 1);
    float* cf = (float*)Cout + (split ? (size_t)blockIdx.z * M * N : 0);
    #pragma unroll
    for (int mi = 0; mi < 4; ++mi)
      #pragma unroll
      for (int nj = 0; nj < 4; ++nj) {
        int col = bn + wc * 64 + nj * 16 + lr;
        if (col < N) {
          #pragma unroll
          for (int r = 0; r < 4; ++r) {
            int row = bm + wr * 64 + mi * 16 + g4 * 4 + r;
            cf[(size_t)row * N + col] = acc[mi][nj][r];
          }
        }
      }
  } else if constexpr (MODE == 2) {
    // Q pack: rope + fragment layout
    const bool rope = (((bn + wc * 64) & 255) == 192);
    unsigned short* Qc = (unsigned short*)Cout;
    #pragma unroll
    for (int mi = 0; mi < 4; ++mi) {
      #pragma unroll
      for (int r = 0; r < 4; ++r) {
        int row = bm + wr * 64 + mi * 16 + g4 * 4 + r;
        float2 c0, c1;
        if (rope) { c0 = cs[row * 32 + lr]; c1 = cs[row * 32 + 16 + lr]; }
        #pragma unroll
        for (int nj = 0; nj < 4; ++nj) {
          float v = acc[mi][nj][r];
          if (rope) {
            float other = acc[mi][nj ^ 2][r];
            float2 cc = (nj & 1) ? c1 : c0;
            v = (nj < 2) ? (v * cc.x - other * cc.y) : (v * cc.x + other * cc.y);
          }
          int col = bn + wc * 64 + nj * 16 + lr;
          int h = col >> 8, i = col & 255;
          size_t addr = ((size_t)(h * 128 + (row >> 4))) * 4096 +
                        ((i >> 3) * 16 + (row & 15)) * 8 + (i & 7);
          Qc[addr] = f2bf(v);
        }
      }
    }
  } else {  // MODE == 3: KV pack
    unsigned short* Kc = (unsigned short*)Cout;
    unsigned short* Vc = (unsigned short*)Cout2;
    #pragma unroll
    for (int mi = 0; mi < 4; ++mi)
      #pragma unroll
      for (int nj = 0; nj < 4; ++nj) {
        int col = bn + wc * 64 + nj * 16 + lr;
        int h = (int)(((unsigned)col * 9363u) >> 22);   // col / 448
        int i = col - h * 448;
        #pragma unroll
        for (int r = 0; r < 4; ++r) {
          int row = bm + wr * 64 + mi * 16 + g4 * 4 + r;
          float v = acc[mi][nj][r];
          size_t tile = ((size_t)(h * 64 + (row >> 5))) * 8192;
          if (i < 192) {
            size_t addr = tile + (((row >> 4) & 1) * 512 + (i >> 3) * 16 + (row & 15)) * 8 + (i & 7);
            Kc[addr] = f2bf(v);
          } else {
            int vc = i - 192;
            size_t addr = tile + ((vc >> 4) * 64 + ((row >> 3) & 3) * 16 + (vc & 15)) * 8 + (row & 7);
            Vc[addr] = f2bf(v);
          }
        }
      }
  }
}

// ---------------- fused 2-part reduce + RMSNorm for q (768 cols) ------------
__global__ __launch_bounds__(256) void rmsnormq_kernel(
    const float* __restrict__ parts, const float* __restrict__ g,
    unsigned short* __restrict__ out, int rowstride, size_t pstride) {
  __shared__ float red[256];
  const int row = blockIdx.x, t = threadIdx.x;
  const float* x = parts + (size_t)row * rowstride;
  float v[3];
  float s = 0.f;
  #pragma unroll
  for (int e = 0; e < 3; ++e) {
    int i = t + 256 * e;
    float a = x[i] + x[i + pstride];
    v[e] = a;
    s += a * a;
  }
  red[t] = s;
  __syncthreads();
  for (int o = 128; o > 0; o >>= 1) {
    if (t < o) red[t] += red[t + o];
    __syncthreads();
  }
  const float scale = rsqrtf(red[0] / 768.f + 1e-6f);
  unsigned short* y = out + (size_t)row * 768;
  #pragma unroll
  for (int e = 0; e < 3; ++e) {
    int i = t + 256 * e;
    y[i] = f2bf(v[e] * scale * g[i]);
  }
}

// ---------------- fused 2-part reduce + RMSNorm kv (512) + rope cols --------
__global__ __launch_bounds__(256) void kv_post_kernel(
    const float* __restrict__ parts, const float* __restrict__ g,
    unsigned short* __restrict__ kv_c, float* __restrict__ rope_out,
    int rowstride, size_t pstride) {
  __shared__ float red[256];
  __shared__ float vals[576];
  const int row = blockIdx.x, t = threadIdx.x;
  const float* x = parts + (size_t)row * rowstride + 768;
  float s = 0.f;
  for (int i = t; i < 576; i += 256) {
    float a = x[i] + x[i + pstride];
    vals[i] = a;
    if (i < 512) s += a * a;
  }
  red[t] = s;
  __syncthreads();
  for (int o = 128; o > 0; o >>= 1) {
    if (t < o) red[t] += red[t + o];
    __syncthreads();
  }
  const float scale = rsqrtf(red[0] / 512.f + 1e-6f);
  for (int i = t; i < 576; i += 256) {
    if (i < 512) kv_c[(size_t)row * 512 + i] = f2bf(vals[i] * scale * g[i]);
    else rope_out[(size_t)row * 64 + (i - 512)] = vals[i];
  }
}

// ---------------- k_rope broadcast into Kc rope columns ---------------------
__global__ __launch_bounds__(256) void krope_kernel(
    const float* __restrict__ rope_src, const float2* __restrict__ cs,
    unsigned short* __restrict__ Kc) {
  const int kt = blockIdx.x;   // 0..63
  const int h = blockIdx.y;    // 0..19
  const int t = threadIdx.x;
  for (int it = t; it < 1024; it += 256) {
    int rowin = it >> 5, j = it & 31;
    int krow = kt * 32 + rowin;
    float x0 = rope_src[krow * 64 + j];
    float x1 = rope_src[krow * 64 + 32 + j];
    float2 cc = cs[krow * 32 + j];
    float v0 = x0 * cc.x - x1 * cc.y;
    float v1 = x1 * cc.x + x0 * cc.y;
    size_t base = ((size_t)(h * 64 + kt)) * 8192;
    int sub = (rowin >> 4) & 1, r15 = rowin & 15;
    int i0 = 192 + j, i1 = 224 + j;
    Kc[base + (sub * 512 + (i0 >> 3) * 16 + r15) * 8 + (i0 & 7)] = f2bf(v0);
    Kc[base + (sub * 512 + (i1 >> 3) * 16 + r15) * 8 + (i1 & 7)] = f2bf(v1);
  }
}

// ---------------- MFMA flash attention: 8-wave QBLK=128, full K/V dbuf ------
// 512 threads = 8 waves, each wave owns 16 q-rows. K/V double-buffered in
// LDS (136KB; 1 block/CU is reg-bound anyway so the extra LDS is free).
// Counted vmcnt(8): next tile's 8 loads/wave stay in flight across barriers.
__global__ __launch_bounds__(512, 1) void attn_mfma(
    const unsigned short* __restrict__ Qc, const unsigned short* __restrict__ Kc,
    const unsigned short* __restrict__ Vc, unsigned short* __restrict__ outp,
    unsigned short* __restrict__ part_O, float* __restrict__ part_ml) {
  __shared__ unsigned short Ks[2][16384] __attribute__((aligned(16)));  // 64KB
  __shared__ unsigned short Vs[2][16384] __attribute__((aligned(16)));  // 64KB
  __shared__ unsigned short Ps[4096] __attribute__((aligned(16)));      // 8KB
  const int t = threadIdx.x;
  const int l = t & 63;
  const int w = t >> 6;        // 0..7
  const int g = l >> 4;
  const int c = l & 15;
  const int b = blockIdx.x;

  int T, h, chunk = 0, ktbeg, ktend;
  bool issplit;
  if (b < 320) {               // T=15..8, two chunks each (T+1 iters)
    T = 15 - b / 40;
    int rem = b % 40;
    h = rem >> 1; chunk = rem & 1;
    issplit = true;
    ktbeg = chunk ? (T + 1) : 0;
    ktend = chunk ? (2 * T + 2) : (T + 1);
  } else {                     // T=7..0 whole (2T+2 <= 16 iters)
    int j = b - 320;
    T = 7 - j / 20;
    h = j % 20;
    issplit = false;
    ktbeg = 0; ktend = 2 * T + 2;
  }

  const unsigned short* qt0 = Qc + ((size_t)(h * 128 + T * 8 + w)) * 4096;
  bf16x8 qf[8];
  #pragma unroll
  for (int st = 0; st < 8; ++st)
    qf[st] = *reinterpret_cast<const bf16x8*>(qt0 + st * 512 + l * 8);

  f32x4 acc[16];
  #pragma unroll
  for (int vt = 0; vt < 16; ++vt) acc[vt] = (f32x4){0.f, 0.f, 0.f, 0.f};
  float m = -1e30f, lsum = 0.f;
  const int qpos = T * 128 + w * 16 + c;
  const int wmax = T * 128 + w * 16 + 15;   // this wave's last q-row

  // waves 0-3 stage K, waves 4-7 stage V
  const int wf = (w & 3) * 4;
  const unsigned short* sbase =
      ((w < 4) ? Kc : Vc) + (size_t)h * 64 * 8192 + wf * 512 + l * 8;

#define ATTN_STAGE(buf, tile)                                                \
  {                                                                          \
    unsigned short* ld_ = (w < 4) ? Ks[buf] : Vs[buf];                       \
    const unsigned short* s0_ = sbase + (size_t)(2 * (tile)) * 8192;         \
    const unsigned short* s1_ = sbase + (size_t)(2 * (tile) + 1) * 8192;     \
    _Pragma("unroll")                                                        \
    for (int j_ = 0; j_ < 4; ++j_)                                           \
      gload_lds16(s0_ + j_ * 512, &ld_[(wf + j_) * 512]);                    \
    _Pragma("unroll")                                                        \
    for (int j_ = 0; j_ < 4; ++j_)                                           \
      gload_lds16(s1_ + j_ * 512, &ld_[8192 + (wf + j_) * 512]);             \
  }

  ATTN_STAGE(0, ktbeg)
  int cur = 0;
  for (int kt = ktbeg; kt < ktend; ++kt) {
    if (kt + 1 < ktend) {
      ATTN_STAGE(cur ^ 1, kt + 1)
      asm volatile("s_waitcnt vmcnt(8)" ::: "memory");   // tile kt landed
    } else {
      asm volatile("s_waitcnt vmcnt(0)" ::: "memory");
    }
    __builtin_amdgcn_s_barrier();

    if (kt * 64 <= wmax) {     // wave-uniform: skip when fully masked
      // QK^T swapped: s[j] rows = k-pos kt*64 + j*16+g*4+r, cols = q-row c
      f32x4 s[4];
      #pragma unroll
      for (int j = 0; j < 4; ++j) s[j] = (f32x4){0.f, 0.f, 0.f, 0.f};
      __builtin_amdgcn_s_setprio(1);
      #pragma unroll
      for (int kk = 0; kk < 2; ++kk)
        #pragma unroll
        for (int st = 0; st < 8; ++st) {
          bf16x8 k0 = *reinterpret_cast<const bf16x8*>(&Ks[cur][kk * 8192 + st * 512 + l * 8]);
          bf16x8 k1 = *reinterpret_cast<const bf16x8*>(&Ks[cur][kk * 8192 + 4096 + st * 512 + l * 8]);
          s[2 * kk]     = __builtin_amdgcn_mfma_f32_16x16x32_bf16(k0, qf[st], s[2 * kk], 0, 0, 0);
          s[2 * kk + 1] = __builtin_amdgcn_mfma_f32_16x16x32_bf16(k1, qf[st], s[2 * kk + 1], 0, 0, 0);
        }
      __builtin_amdgcn_s_setprio(0);

      const bool masked = (kt * 64 + 63 > qpos);
      float a[4][4];
      #pragma unroll
      for (int j = 0; j < 4; ++j)
        #pragma unroll
        for (int r = 0; r < 4; ++r) {
          a[j][r] = s[j][r] * 0.0625f;
          if (masked && (kt * 64 + j * 16 + g * 4 + r > qpos)) a[j][r] = -1e30f;
        }
      float mx = -1e30f;
      #pragma unroll
      for (int j = 0; j < 4; ++j)
        mx = fmaxf(mx, fmaxf(fmaxf(a[j][0], a[j][1]), fmaxf(a[j][2], a[j][3])));
      mx = fmaxf(mx, __shfl_xor(mx, 16));
      mx = fmaxf(mx, __shfl_xor(mx, 32));
      float rs;
      if (mx > m + 8.f) { rs = __expf(m - mx); m = mx; } else { rs = 1.f; }
      float e[4][4];
      float sum = 0.f;
      #pragma unroll
      for (int j = 0; j < 4; ++j)
        #pragma unroll
        for (int r = 0; r < 4; ++r) { e[j][r] = __expf(a[j][r] - m); sum += e[j][r]; }
      sum += __shfl_xor(sum, 16);
      sum += __shfl_xor(sum, 32);
      lsum = lsum * rs + sum;

      if (rs != 1.f) {
        #pragma unroll
        for (int vt = 0; vt < 16; ++vt) {
          acc[vt][0] *= rs; acc[vt][1] *= rs; acc[vt][2] *= rs; acc[vt][3] *= rs;
        }
      }

      // per 32-k slab: write P into wave's 512-short region, then PV.
      #pragma unroll
      for (int ks = 0; ks < 2; ++ks) {
        #pragma unroll
        for (int jj = 0; jj < 2; ++jj) {
          int j = 2 * ks + jj;
          int pbase = w * 512 + (2 * jj + (g >> 1)) * 128 + c * 8 + (g & 1) * 4;
          uint2 pw;
          pw.x = pk2(e[j][0], e[j][1]);
          pw.y = pk2(e[j][2], e[j][3]);
          *reinterpret_cast<uint2*>(&Ps[pbase]) = pw;
        }
        bf16x8 pa = *reinterpret_cast<const bf16x8*>(&Ps[w * 512 + l * 8]);
        __builtin_amdgcn_s_setprio(1);
        #pragma unroll
        for (int vt = 0; vt < 16; ++vt) {
          bf16x8 vb = *reinterpret_cast<const bf16x8*>(&Vs[cur][ks * 8192 + vt * 512 + l * 8]);
          acc[vt] = __builtin_amdgcn_mfma_f32_16x16x32_bf16(vb, pa, acc[vt], 0, 0, 0);
        }
        __builtin_amdgcn_s_setprio(0);
      }
    }
    __syncthreads();   // all readers of buf cur done (next iter stages into it)
    cur ^= 1;
  }
#undef ATTN_STAGE

  const float inv = 1.f / lsum;
  const int lrow = w * 16 + c;
  if (!issplit) {
    const int row = T * 128 + lrow;
    unsigned short* orow = outp + (size_t)row * 5120 + h * 256 + g * 4;
    #pragma unroll
    for (int vt = 0; vt < 16; ++vt) {
      uint2 o;
      o.x = pk2(acc[vt][0] * inv, acc[vt][1] * inv);
      o.y = pk2(acc[vt][2] * inv, acc[vt][3] * inv);
      *reinterpret_cast<uint2*>(orow + vt * 16) = o;
    }
  } else {
    const int pidx = ((T - 8) * 20 + h) * 2 + chunk;
    unsigned short* po = part_O + (size_t)pidx * 32768 + lrow * 256 + g * 4;
    #pragma unroll
    for (int vt = 0; vt < 16; ++vt) {
      uint2 o;
      o.x = pk2(acc[vt][0] * inv, acc[vt][1] * inv);
      o.y = pk2(acc[vt][2] * inv, acc[vt][3] * inv);
      *reinterpret_cast<uint2*>(po + vt * 16) = o;
    }
    if (g == 0)
      *reinterpret_cast<float2*>(&part_ml[(size_t)(pidx * 128 + lrow) * 2]) =
          make_float2(m, lsum);
  }
}

// ---------------- flash-combine merge for split tasks (128 rows) ------------
__global__ __launch_bounds__(256) void attn_merge_kernel(
    const unsigned short* __restrict__ part_O, const float* __restrict__ part_ml,
    unsigned short* __restrict__ outp) {
  const int b = blockIdx.x;        // 0..159: T = 8 + b/20, h = b%20
  const int T = 8 + b / 20;
  const int h = b % 20;
  const int t = threadIdx.x;
  const int lr = t >> 1;           // local row 0..127
  const int c0 = (t & 1) * 128;    // col base
  const int p0 = ((T - 8) * 20 + h) * 2;
  float m1 = part_ml[(size_t)(p0 * 128 + lr) * 2];
  float l1 = part_ml[(size_t)(p0 * 128 + lr) * 2 + 1];
  float m2 = part_ml[(size_t)((p0 + 1) * 128 + lr) * 2];
  float l2 = part_ml[(size_t)((p0 + 1) * 128 + lr) * 2 + 1];
  float M = fmaxf(m1, m2);
  float w1 = __expf(m1 - M) * l1, w2 = __expf(m2 - M) * l2;
  float inv = 1.f / (w1 + w2);
  w1 *= inv; w2 *= inv;
  const unsigned short* o1 = part_O + (size_t)p0 * 32768 + lr * 256 + c0;
  const unsigned short* o2 = part_O + (size_t)(p0 + 1) * 32768 + lr * 256 + c0;
  unsigned short* dst = outp + (size_t)(T * 128 + lr) * 5120 + h * 256 + c0;
  for (int j = 0; j < 128; j += 8) {
    bf16x8 a = *reinterpret_cast<const bf16x8*>(o1 + j);
    bf16x8 bb = *reinterpret_cast<const bf16x8*>(o2 + j);
    union { unsigned short u[8]; uint4 v; } o;
    #pragma unroll
    for (int e = 0; e < 8; ++e)
      o.u[e] = f2bf(w1 * bf2f((unsigned short)a[e]) + w2 * bf2f((unsigned short)bb[e]));
    *reinterpret_cast<uint4*>(dst + j) = o.v;
  }
}

extern "C" void kernel_launch(void* const* d_in, const int* in_sizes, int n_in,
                              void* d_out, int out_size, void* d_ws, size_t ws_size,
                              hipStream_t stream) {
  const float* hidden = (const float*)d_in[0];
  const float* w_q_a  = (const float*)d_in[1];
  const float* w_q_b  = (const float*)d_in[2];
  const float* w_kv_a = (const float*)d_in[3];
  const float* w_kv_b = (const float*)d_in[4];
  const float* w_o    = (const float*)d_in[5];
  const float* g_q_a  = (const float*)d_in[6];
  const float* g_kv_a = (const float*)d_in[7];
  float* out = (float*)d_out;

  const int S = 2048;
  char* ws = (char*)d_ws;
  // overlay plan; peak ~143 MB
  unsigned short* wo_t     = (unsigned short*)(ws + 0);          // [2048,5120] bf16
  unsigned short* wcat     = (unsigned short*)(ws + 20971520);   // [1344,2048] bf16
  unsigned short* wqb_t    = (unsigned short*)(ws + 26476544);   // [5120,768]
  unsigned short* wkvb_t   = (unsigned short*)(ws + 34340864);   // [8960,512]
  unsigned short* hid_bf   = (unsigned short*)(ws + 43515904);   // [2048,2048]
  float*          a_part   = (float*)(ws + 52428800);            // 22MB (S2 only)
  unsigned short* Qc       = (unsigned short*)(ws + 52428800);   // 21MB (S3+)
  unsigned short* Kc       = (unsigned short*)(ws + 73400320);   // 21MB
  unsigned short* Vc       = (unsigned short*)(ws + 94371840);   // 21MB
  unsigned short* q_c      = (unsigned short*)(ws + 115343360);  // [2048,768] bf16
  unsigned short* kv_c     = (unsigned short*)(ws + 118489088);  // [2048,512] bf16
  float*          ckv_rope = (float*)(ws + 120586240);           // [2048,64] f32
  float2*         rope_cs  = (float2*)(ws + 121110528);          // [2048,32] float2
  unsigned short* attn_bf  = (unsigned short*)(ws + 121634816);  // [2048,5120] bf16
  // S4 overlays (wqb_t/wkvb_t/hid_bf dead by attention time):
  unsigned short* part_O   = (unsigned short*)(ws + 26476544);   // 320 x 64KB = 21MB
  float*          part_ml  = (float*)(ws + 47448064);            // 320 x 1KB
  float*          wo_part  = (float*)(ws + 26476544);            // 67MB (S5 only; Qc/Kc dead)

  dim3 blk(256);
  dim3 tblk(32, 8);

  // S1: conversions / transposes / tables
  f32_to_bf16_kernel<<<2048, blk, 0, stream>>>(hidden, hid_bf, S * 2048 / 8);
  transpose_f32_bf16<<<dim3(768 / 32, 2048 / 32), tblk, 0, stream>>>(w_q_a, wcat, 2048, 768);
  transpose_f32_bf16<<<dim3(576 / 32, 2048 / 32), tblk, 0, stream>>>(
      w_kv_a, wcat + (size_t)768 * 2048, 2048, 576);
  transpose_f32_bf16<<<dim3(5120 / 32, 768 / 32), tblk, 0, stream>>>(w_q_b, wqb_t, 768, 5120);
  transpose_f32_bf16<<<dim3(8960 / 32, 512 / 32), tblk, 0, stream>>>(w_kv_b, wkvb_t, 512, 8960);
  transpose_f32_bf16<<<dim3(2048 / 32, 5120 / 32), tblk, 0, stream>>>(w_o, wo_t, 5120, 2048);
  rope_table_kernel<<<256, blk, 0, stream>>>(rope_cs);

  // S2: merged a-projection (N=1344, split-K 2) + norms
  gemm_mfma<0><<<dim3(11, 16, 2), blk, 0, stream>>>(
      hid_bf, wcat, a_part, nullptr, nullptr, S, 1344, 2048, 1024);
  rmsnormq_kernel<<<S, blk, 0, stream>>>(a_part, g_q_a, q_c, 1344, (size_t)S * 1344);
  kv_post_kernel<<<S, blk, 0, stream>>>(a_part, g_kv_a, kv_c, ckv_rope, 1344, (size_t)S * 1344);

  // S3: b-projections with fused pack epilogues
  gemm_mfma<2><<<dim3(40, 16, 1), blk, 0, stream>>>(
      q_c, wqb_t, Qc, nullptr, rope_cs, S, 5120, 768, 768);
  gemm_mfma<3><<<dim3(70, 16, 1), blk, 0, stream>>>(
      kv_c, wkvb_t, Kc, Vc, nullptr, S, 8960, 512, 512);
  krope_kernel<<<dim3(64, NHEADS), blk, 0, stream>>>(ckv_rope, rope_cs, Kc);

  // S4: attention (480 static blocks of 512 threads, QBLK=128, dbuf) + merge
  attn_mfma<<<480, dim3(512), 0, stream>>>(Qc, Kc, Vc, attn_bf, part_O, part_ml);
  attn_merge_kernel<<<160, blk, 0, stream>>>(part_O, part_ml, attn_bf);

  // S5: output projection (split-K 4) + reduce
  gemm_mfma<0><<<dim3(16, 16, 4), blk, 0, stream>>>(
      attn_bf, wo_t, wo_part, nullptr, nullptr, S, 2048, 5120, 1280);
  reduce_add_kernel<<<(S * 2048 / 4 + 255) / 256, blk, 0, stream>>>(
      wo_part, out, S * 2048 / 4, 4, (size_t)S * 2048 / 4);
}

// Round 13
// 371.284 us; speedup vs baseline: 1.0380x; 1.0380x over previous
//
#include <hip/hip_runtime.h>
#include <hip/hip_bf16.h>
#include <math.h>

#define NHEADS 20

typedef short bf16x8 __attribute__((ext_vector_type(8)));
typedef float f32x4 __attribute__((ext_vector_type(4)));

__device__ inline float bf2f(unsigned short u) {
  union { unsigned int i; float f; } x; x.i = ((unsigned int)u) << 16; return x.f;
}
__device__ inline unsigned short f2bf(float f) {
  __hip_bfloat16 h = __float2bfloat16(f);
  union { __hip_bfloat16 h; unsigned short u; } x; x.h = h; return x.u;
}
__device__ inline unsigned int pk2(float a, float b) {
  return (unsigned int)f2bf(a) | ((unsigned int)f2bf(b) << 16);
}
__device__ inline void gload_lds16(const void* g, void* l) {
  __builtin_amdgcn_global_load_lds(
      (const __attribute__((address_space(1))) void*)g,
      (__attribute__((address_space(3))) void*)l, 16, 0, 0);
}

// ---------------- fp32 -> bf16 copy (8 elems/thread) ------------------------
__global__ __launch_bounds__(256) void f32_to_bf16_kernel(
    const float* __restrict__ in, unsigned short* __restrict__ out, int n8) {
  int idx = blockIdx.x * 256 + threadIdx.x;
  if (idx < n8) {
    float4 a = reinterpret_cast<const float4*>(in)[idx * 2];
    float4 b = reinterpret_cast<const float4*>(in)[idx * 2 + 1];
    union { unsigned short u[8]; uint4 v; } o;
    o.u[0] = f2bf(a.x); o.u[1] = f2bf(a.y); o.u[2] = f2bf(a.z); o.u[3] = f2bf(a.w);
    o.u[4] = f2bf(b.x); o.u[5] = f2bf(b.y); o.u[6] = f2bf(b.z); o.u[7] = f2bf(b.w);
    reinterpret_cast<uint4*>(out)[idx] = o.v;
  }
}

// ---------------- rope cos/sin table: cs[pos*32+fi] -------------------------
__global__ __launch_bounds__(256) void rope_table_kernel(float2* __restrict__ cs) {
  int idx = blockIdx.x * 256 + threadIdx.x;   // 2048*32
  int pos = idx >> 5, fi = idx & 31;
  float inv = exp2f(-(float)fi * 0.622861517f);   // 1e6^(-fi/32)
  float ang = (float)pos * inv;
  cs[idx] = make_float2(cosf(ang), sinf(ang));
}

// ---------------- fp32 [R,C] -> bf16 transposed [C,R] -----------------------
__global__ __launch_bounds__(256) void transpose_f32_bf16(
    const float* __restrict__ in, unsigned short* __restrict__ out, int R, int C0) {
  __shared__ float tile[32][33];
  const int tx = threadIdx.x, ty = threadIdx.y;
  const int bc = blockIdx.x * 32, br = blockIdx.y * 32;
  #pragma unroll
  for (int j = 0; j < 4; ++j)
    tile[ty + 8 * j][tx] = in[(size_t)(br + ty + 8 * j) * C0 + bc + tx];
  __syncthreads();
  #pragma unroll
  for (int j = 0; j < 4; ++j)
    out[(size_t)(bc + ty + 8 * j) * R + br + tx] = f2bf(tile[tx][ty + 8 * j]);
}

// ---------------- elementwise multi-part reduce (float4) --------------------
__global__ __launch_bounds__(256) void reduce_add_kernel(
    const float* __restrict__ in, float* __restrict__ out, int n4, int parts, size_t stride4) {
  int idx = blockIdx.x * 256 + threadIdx.x;
  if (idx < n4) {
    const float4* in4 = reinterpret_cast<const float4*>(in);
    float4 s = in4[idx];
    for (int p = 1; p < parts; ++p) {
      float4 b = in4[idx + p * stride4];
      s.x += b.x; s.y += b.y; s.z += b.z; s.w += b.w;
    }
    reinterpret_cast<float4*>(out)[idx] = s;
  }
}

// ---------------- bf16 MFMA GEMM, 2-phase dbuf, BK=32 -----------------------
// MODE 0: f32 out (split-K partials if gridDim.z>1)
// MODE 2: Q-pack epilogue: rope (cs table) + write Qc fragment layout
// MODE 3: KV-pack epilogue: write Kc nope + Vc fragment layouts
template <int MODE>
__global__ __launch_bounds__(256) void gemm_mfma(
    const unsigned short* __restrict__ A, const unsigned short* __restrict__ Bt,
    void* __restrict__ Cout, void* __restrict__ Cout2, const float2* __restrict__ cs,
    int M, int N, int K, int ksize) {
  __shared__ unsigned short As[2][4096] __attribute__((aligned(16)));
  __shared__ unsigned short Bs[2][4096] __attribute__((aligned(16)));
  const int t = threadIdx.x;
  const int l = t & 63;
  const int w = t >> 6;
  const int bm = blockIdx.y * 128;
  const int bn = blockIdx.x * 128;
  const int kbase = blockIdx.z * ksize;
  const int wr = w >> 1, wc = w & 1;
  const int lr = l & 15, lk = (l >> 4) * 8;
  const int g4 = l >> 4;

  f32x4 acc[4][4];
  #pragma unroll
  for (int i = 0; i < 4; ++i)
    #pragma unroll
    for (int j = 0; j < 4; ++j) acc[i][j] = (f32x4){0.f, 0.f, 0.f, 0.f};

  int arow0 = bm + (w + 0) * 16 + lr;
  int arow1 = bm + (w + 4) * 16 + lr;
  int bcol0 = bn + (w + 0) * 16 + lr; if (bcol0 >= N) bcol0 = N - 1;
  int bcol1 = bn + (w + 4) * 16 + lr; if (bcol1 >= N) bcol1 = N - 1;
  const unsigned short* aptr0 = A + (size_t)arow0 * K + kbase + lk;
  const unsigned short* aptr1 = A + (size_t)arow1 * K + kbase + lk;
  const unsigned short* bptr0 = Bt + (size_t)bcol0 * K + kbase + lk;
  const unsigned short* bptr1 = Bt + (size_t)bcol1 * K + kbase + lk;

#define GEMM_STAGE(buf, koff)                                  \
  gload_lds16(aptr0 + (koff), &As[buf][(w + 0) * 512]);        \
  gload_lds16(aptr1 + (koff), &As[buf][(w + 4) * 512]);        \
  gload_lds16(bptr0 + (koff), &Bs[buf][(w + 0) * 512]);        \
  gload_lds16(bptr1 + (koff), &Bs[buf][(w + 4) * 512]);

  GEMM_STAGE(0, 0)
  int cur = 0;
  for (int k0 = 0; k0 < ksize; k0 += 32) {
    if (k0 + 32 < ksize) {
      GEMM_STAGE(cur ^ 1, k0 + 32)
      asm volatile("s_waitcnt vmcnt(4)" ::: "memory");
    } else {
      asm volatile("s_waitcnt vmcnt(0)" ::: "memory");
    }
    __builtin_amdgcn_s_barrier();
    bf16x8 af[4], bfr[4];
    #pragma unroll
    for (int mi = 0; mi < 4; ++mi)
      af[mi] = *reinterpret_cast<const bf16x8*>(&As[cur][(wr * 4 + mi) * 512 + l * 8]);
    #pragma unroll
    for (int nj = 0; nj < 4; ++nj)
      bfr[nj] = *reinterpret_cast<const bf16x8*>(&Bs[cur][(wc * 4 + nj) * 512 + l * 8]);
    #pragma unroll
    for (int mi = 0; mi < 4; ++mi)
      #pragma unroll
      for (int nj = 0; nj < 4; ++nj)
        acc[mi][nj] = __builtin_amdgcn_mfma_f32_16x16x32_bf16(af[mi], bfr[nj], acc[mi][nj], 0, 0, 0);
    __builtin_amdgcn_s_barrier();
    cur ^= 1;
  }
#undef GEMM_STAGE

  if constexpr (MODE == 0) {
    const bool split = (gridDim.z > 1);
    float* cf = (float*)Cout + (split ? (size_t)blockIdx.z * M * N : 0);
    #pragma unroll
    for (int mi = 0; mi < 4; ++mi)
      #pragma unroll
      for (int nj = 0; nj < 4; ++nj) {
        int col = bn + wc * 64 + nj * 16 + lr;
        if (col < N) {
          #pragma unroll
          for (int r = 0; r < 4; ++r) {
            int row = bm + wr * 64 + mi * 16 + g4 * 4 + r;
            cf[(size_t)row * N + col] = acc[mi][nj][r];
          }
        }
      }
  } else if constexpr (MODE == 2) {
    // Q pack: rope + fragment layout
    const bool rope = (((bn + wc * 64) & 255) == 192);
    unsigned short* Qc = (unsigned short*)Cout;
    #pragma unroll
    for (int mi = 0; mi < 4; ++mi) {
      #pragma unroll
      for (int r = 0; r < 4; ++r) {
        int row = bm + wr * 64 + mi * 16 + g4 * 4 + r;
        float2 c0, c1;
        if (rope) { c0 = cs[row * 32 + lr]; c1 = cs[row * 32 + 16 + lr]; }
        #pragma unroll
        for (int nj = 0; nj < 4; ++nj) {
          float v = acc[mi][nj][r];
          if (rope) {
            float other = acc[mi][nj ^ 2][r];
            float2 cc = (nj & 1) ? c1 : c0;
            v = (nj < 2) ? (v * cc.x - other * cc.y) : (v * cc.x + other * cc.y);
          }
          int col = bn + wc * 64 + nj * 16 + lr;
          int h = col >> 8, i = col & 255;
          size_t addr = ((size_t)(h * 128 + (row >> 4))) * 4096 +
                        ((i >> 3) * 16 + (row & 15)) * 8 + (i & 7);
          Qc[addr] = f2bf(v);
        }
      }
    }
  } else {  // MODE == 3: KV pack
    unsigned short* Kc = (unsigned short*)Cout;
    unsigned short* Vc = (unsigned short*)Cout2;
    #pragma unroll
    for (int mi = 0; mi < 4; ++mi)
      #pragma unroll
      for (int nj = 0; nj < 4; ++nj) {
        int col = bn + wc * 64 + nj * 16 + lr;
        int h = (int)(((unsigned)col * 9363u) >> 22);   // col / 448
        int i = col - h * 448;
        #pragma unroll
        for (int r = 0; r < 4; ++r) {
          int row = bm + wr * 64 + mi * 16 + g4 * 4 + r;
          float v = acc[mi][nj][r];
          size_t tile = ((size_t)(h * 64 + (row >> 5))) * 8192;
          if (i < 192) {
            size_t addr = tile + (((row >> 4) & 1) * 512 + (i >> 3) * 16 + (row & 15)) * 8 + (i & 7);
            Kc[addr] = f2bf(v);
          } else {
            int vc = i - 192;
            size_t addr = tile + ((vc >> 4) * 64 + ((row >> 3) & 3) * 16 + (vc & 15)) * 8 + (row & 7);
            Vc[addr] = f2bf(v);
          }
        }
      }
  }
}

// ---------------- w_o GEMM: BK=64, 128x128, split-K 2, f32 partials ---------
// 32 MFMA + 16 ds_read_b128 per wave per barrier-pair (2x BK=32) -> halves
// barrier/waitcnt overhead. LDS 64KB dbuf, 2 blocks/CU, counted vmcnt(8).
__global__ __launch_bounds__(256) void gemm_wo(
    const unsigned short* __restrict__ A, const unsigned short* __restrict__ Bt,
    float* __restrict__ Cout, int M, int N, int K, int ksize) {
  __shared__ unsigned short As[2][8192] __attribute__((aligned(16)));
  __shared__ unsigned short Bs[2][8192] __attribute__((aligned(16)));
  const int t = threadIdx.x;
  const int l = t & 63;
  const int w = t >> 6;
  const int bm = blockIdx.y * 128;
  const int bn = blockIdx.x * 128;
  const int kbase = blockIdx.z * ksize;
  const int wr = w >> 1, wc = w & 1;
  const int lr = l & 15, lk = (l >> 4) * 8;
  const int g4 = l >> 4;

  f32x4 acc[4][4];
  #pragma unroll
  for (int i = 0; i < 4; ++i)
    #pragma unroll
    for (int j = 0; j < 4; ++j) acc[i][j] = (f32x4){0.f, 0.f, 0.f, 0.f};

  const unsigned short* aptr0 = A + (size_t)(bm + (w + 0) * 16 + lr) * K + kbase + lk;
  const unsigned short* aptr1 = A + (size_t)(bm + (w + 4) * 16 + lr) * K + kbase + lk;
  const unsigned short* bptr0 = Bt + (size_t)(bn + (w + 0) * 16 + lr) * K + kbase + lk;
  const unsigned short* bptr1 = Bt + (size_t)(bn + (w + 4) * 16 + lr) * K + kbase + lk;

#define WO_STAGE(buf, koff)                                                   \
  _Pragma("unroll")                                                           \
  for (int kh = 0; kh < 2; ++kh) {                                            \
    gload_lds16(aptr0 + (koff) + kh * 32, &As[buf][(kh * 8 + w + 0) * 512]);  \
    gload_lds16(aptr1 + (koff) + kh * 32, &As[buf][(kh * 8 + w + 4) * 512]);  \
    gload_lds16(bptr0 + (koff) + kh * 32, &Bs[buf][(kh * 8 + w + 0) * 512]);  \
    gload_lds16(bptr1 + (koff) + kh * 32, &Bs[buf][(kh * 8 + w + 4) * 512]);  \
  }

  WO_STAGE(0, 0)
  int cur = 0;
  for (int k0 = 0; k0 < ksize; k0 += 64) {
    if (k0 + 64 < ksize) {
      WO_STAGE(cur ^ 1, k0 + 64)
      asm volatile("s_waitcnt vmcnt(8)" ::: "memory");
    } else {
      asm volatile("s_waitcnt vmcnt(0)" ::: "memory");
    }
    __builtin_amdgcn_s_barrier();
    #pragma unroll
    for (int kh = 0; kh < 2; ++kh) {
      bf16x8 af[4], bfr[4];
      #pragma unroll
      for (int mi = 0; mi < 4; ++mi)
        af[mi] = *reinterpret_cast<const bf16x8*>(&As[cur][(kh * 8 + wr * 4 + mi) * 512 + l * 8]);
      #pragma unroll
      for (int nj = 0; nj < 4; ++nj)
        bfr[nj] = *reinterpret_cast<const bf16x8*>(&Bs[cur][(kh * 8 + wc * 4 + nj) * 512 + l * 8]);
      #pragma unroll
      for (int mi = 0; mi < 4; ++mi)
        #pragma unroll
        for (int nj = 0; nj < 4; ++nj)
          acc[mi][nj] = __builtin_amdgcn_mfma_f32_16x16x32_bf16(af[mi], bfr[nj], acc[mi][nj], 0, 0, 0);
    }
    __builtin_amdgcn_s_barrier();
    cur ^= 1;
  }
#undef WO_STAGE

  float* cf = Cout + (size_t)blockIdx.z * M * N;
  #pragma unroll
  for (int mi = 0; mi < 4; ++mi)
    #pragma unroll
    for (int nj = 0; nj < 4; ++nj) {
      int col = bn + wc * 64 + nj * 16 + lr;
      #pragma unroll
      for (int r = 0; r < 4; ++r) {
        int row = bm + wr * 64 + mi * 16 + g4 * 4 + r;
        cf[(size_t)row * N + col] = acc[mi][nj][r];
      }
    }
}

// ---------------- fused 2-part reduce + RMSNorm for q (768 cols) ------------
__global__ __launch_bounds__(256) void rmsnormq_kernel(
    const float* __restrict__ parts, const float* __restrict__ g,
    unsigned short* __restrict__ out, int rowstride, size_t pstride) {
  __shared__ float red[256];
  const int row = blockIdx.x, t = threadIdx.x;
  const float* x = parts + (size_t)row * rowstride;
  float v[3];
  float s = 0.f;
  #pragma unroll
  for (int e = 0; e < 3; ++e) {
    int i = t + 256 * e;
    float a = x[i] + x[i + pstride];
    v[e] = a;
    s += a * a;
  }
  red[t] = s;
  __syncthreads();
  for (int o = 128; o > 0; o >>= 1) {
    if (t < o) red[t] += red[t + o];
    __syncthreads();
  }
  const float scale = rsqrtf(red[0] / 768.f + 1e-6f);
  unsigned short* y = out + (size_t)row * 768;
  #pragma unroll
  for (int e = 0; e < 3; ++e) {
    int i = t + 256 * e;
    y[i] = f2bf(v[e] * scale * g[i]);
  }
}

// ---------------- fused 2-part reduce + RMSNorm kv (512) + rope cols --------
__global__ __launch_bounds__(256) void kv_post_kernel(
    const float* __restrict__ parts, const float* __restrict__ g,
    unsigned short* __restrict__ kv_c, float* __restrict__ rope_out,
    int rowstride, size_t pstride) {
  __shared__ float red[256];
  __shared__ float vals[576];
  const int row = blockIdx.x, t = threadIdx.x;
  const float* x = parts + (size_t)row * rowstride + 768;
  float s = 0.f;
  for (int i = t; i < 576; i += 256) {
    float a = x[i] + x[i + pstride];
    vals[i] = a;
    if (i < 512) s += a * a;
  }
  red[t] = s;
  __syncthreads();
  for (int o = 128; o > 0; o >>= 1) {
    if (t < o) red[t] += red[t + o];
    __syncthreads();
  }
  const float scale = rsqrtf(red[0] / 512.f + 1e-6f);
  for (int i = t; i < 576; i += 256) {
    if (i < 512) kv_c[(size_t)row * 512 + i] = f2bf(vals[i] * scale * g[i]);
    else rope_out[(size_t)row * 64 + (i - 512)] = vals[i];
  }
}

// ---------------- k_rope broadcast into Kc rope columns ---------------------
__global__ __launch_bounds__(256) void krope_kernel(
    const float* __restrict__ rope_src, const float2* __restrict__ cs,
    unsigned short* __restrict__ Kc) {
  const int kt = blockIdx.x;   // 0..63
  const int h = blockIdx.y;    // 0..19
  const int t = threadIdx.x;
  for (int it = t; it < 1024; it += 256) {
    int rowin = it >> 5, j = it & 31;
    int krow = kt * 32 + rowin;
    float x0 = rope_src[krow * 64 + j];
    float x1 = rope_src[krow * 64 + 32 + j];
    float2 cc = cs[krow * 32 + j];
    float v0 = x0 * cc.x - x1 * cc.y;
    float v1 = x1 * cc.x + x0 * cc.y;
    size_t base = ((size_t)(h * 64 + kt)) * 8192;
    int sub = (rowin >> 4) & 1, r15 = rowin & 15;
    int i0 = 192 + j, i1 = 224 + j;
    Kc[base + (sub * 512 + (i0 >> 3) * 16 + r15) * 8 + (i0 & 7)] = f2bf(v0);
    Kc[base + (sub * 512 + (i1 >> 3) * 16 + r15) * 8 + (i1 & 7)] = f2bf(v1);
  }
}

// ---------------- MFMA flash attention: 8-wave QBLK=128, full K/V dbuf ------
__global__ __launch_bounds__(512, 1) void attn_mfma(
    const unsigned short* __restrict__ Qc, const unsigned short* __restrict__ Kc,
    const unsigned short* __restrict__ Vc, unsigned short* __restrict__ outp,
    unsigned short* __restrict__ part_O, float* __restrict__ part_ml) {
  __shared__ unsigned short Ks[2][16384] __attribute__((aligned(16)));  // 64KB
  __shared__ unsigned short Vs[2][16384] __attribute__((aligned(16)));  // 64KB
  __shared__ unsigned short Ps[4096] __attribute__((aligned(16)));      // 8KB
  const int t = threadIdx.x;
  const int l = t & 63;
  const int w = t >> 6;        // 0..7
  const int g = l >> 4;
  const int c = l & 15;
  const int b = blockIdx.x;

  int T, h, chunk = 0, ktbeg, ktend;
  bool issplit;
  if (b < 320) {               // T=15..8, two chunks each (T+1 iters)
    T = 15 - b / 40;
    int rem = b % 40;
    h = rem >> 1; chunk = rem & 1;
    issplit = true;
    ktbeg = chunk ? (T + 1) : 0;
    ktend = chunk ? (2 * T + 2) : (T + 1);
  } else {                     // T=7..0 whole (2T+2 <= 16 iters)
    int j = b - 320;
    T = 7 - j / 20;
    h = j % 20;
    issplit = false;
    ktbeg = 0; ktend = 2 * T + 2;
  }

  const unsigned short* qt0 = Qc + ((size_t)(h * 128 + T * 8 + w)) * 4096;
  bf16x8 qf[8];
  #pragma unroll
  for (int st = 0; st < 8; ++st)
    qf[st] = *reinterpret_cast<const bf16x8*>(qt0 + st * 512 + l * 8);

  f32x4 acc[16];
  #pragma unroll
  for (int vt = 0; vt < 16; ++vt) acc[vt] = (f32x4){0.f, 0.f, 0.f, 0.f};
  float m = -1e30f, lsum = 0.f;
  const int qpos = T * 128 + w * 16 + c;
  const int wmax = T * 128 + w * 16 + 15;   // this wave's last q-row

  // waves 0-3 stage K, waves 4-7 stage V
  const int wf = (w & 3) * 4;
  const unsigned short* sbase =
      ((w < 4) ? Kc : Vc) + (size_t)h * 64 * 8192 + wf * 512 + l * 8;

#define ATTN_STAGE(buf, tile)                                                \
  {                                                                          \
    unsigned short* ld_ = (w < 4) ? Ks[buf] : Vs[buf];                       \
    const unsigned short* s0_ = sbase + (size_t)(2 * (tile)) * 8192;         \
    const unsigned short* s1_ = sbase + (size_t)(2 * (tile) + 1) * 8192;     \
    _Pragma("unroll")                                                        \
    for (int j_ = 0; j_ < 4; ++j_)                                           \
      gload_lds16(s0_ + j_ * 512, &ld_[(wf + j_) * 512]);                    \
    _Pragma("unroll")                                                        \
    for (int j_ = 0; j_ < 4; ++j_)                                           \
      gload_lds16(s1_ + j_ * 512, &ld_[8192 + (wf + j_) * 512]);             \
  }

  ATTN_STAGE(0, ktbeg)
  int cur = 0;
  for (int kt = ktbeg; kt < ktend; ++kt) {
    if (kt + 1 < ktend) {
      ATTN_STAGE(cur ^ 1, kt + 1)
      asm volatile("s_waitcnt vmcnt(8)" ::: "memory");   // tile kt landed
    } else {
      asm volatile("s_waitcnt vmcnt(0)" ::: "memory");
    }
    __builtin_amdgcn_s_barrier();

    if (kt * 64 <= wmax) {     // wave-uniform: skip when fully masked
      f32x4 s[4];
      #pragma unroll
      for (int j = 0; j < 4; ++j) s[j] = (f32x4){0.f, 0.f, 0.f, 0.f};
      __builtin_amdgcn_s_setprio(1);
      #pragma unroll
      for (int kk = 0; kk < 2; ++kk)
        #pragma unroll
        for (int st = 0; st < 8; ++st) {
          bf16x8 k0 = *reinterpret_cast<const bf16x8*>(&Ks[cur][kk * 8192 + st * 512 + l * 8]);
          bf16x8 k1 = *reinterpret_cast<const bf16x8*>(&Ks[cur][kk * 8192 + 4096 + st * 512 + l * 8]);
          s[2 * kk]     = __builtin_amdgcn_mfma_f32_16x16x32_bf16(k0, qf[st], s[2 * kk], 0, 0, 0);
          s[2 * kk + 1] = __builtin_amdgcn_mfma_f32_16x16x32_bf16(k1, qf[st], s[2 * kk + 1], 0, 0, 0);
        }
      __builtin_amdgcn_s_setprio(0);

      const bool masked = (kt * 64 + 63 > qpos);
      float a[4][4];
      #pragma unroll
      for (int j = 0; j < 4; ++j)
        #pragma unroll
        for (int r = 0; r < 4; ++r) {
          a[j][r] = s[j][r] * 0.0625f;
          if (masked && (kt * 64 + j * 16 + g * 4 + r > qpos)) a[j][r] = -1e30f;
        }
      float mx = -1e30f;
      #pragma unroll
      for (int j = 0; j < 4; ++j)
        mx = fmaxf(mx, fmaxf(fmaxf(a[j][0], a[j][1]), fmaxf(a[j][2], a[j][3])));
      mx = fmaxf(mx, __shfl_xor(mx, 16));
      mx = fmaxf(mx, __shfl_xor(mx, 32));
      float rs;
      if (mx > m + 8.f) { rs = __expf(m - mx); m = mx; } else { rs = 1.f; }
      float e[4][4];
      float sum = 0.f;
      #pragma unroll
      for (int j = 0; j < 4; ++j)
        #pragma unroll
        for (int r = 0; r < 4; ++r) { e[j][r] = __expf(a[j][r] - m); sum += e[j][r]; }
      sum += __shfl_xor(sum, 16);
      sum += __shfl_xor(sum, 32);
      lsum = lsum * rs + sum;

      if (rs != 1.f) {
        #pragma unroll
        for (int vt = 0; vt < 16; ++vt) {
          acc[vt][0] *= rs; acc[vt][1] *= rs; acc[vt][2] *= rs; acc[vt][3] *= rs;
        }
      }

      #pragma unroll
      for (int ks = 0; ks < 2; ++ks) {
        #pragma unroll
        for (int jj = 0; jj < 2; ++jj) {
          int j = 2 * ks + jj;
          int pbase = w * 512 + (2 * jj + (g >> 1)) * 128 + c * 8 + (g & 1) * 4;
          uint2 pw;
          pw.x = pk2(e[j][0], e[j][1]);
          pw.y = pk2(e[j][2], e[j][3]);
          *reinterpret_cast<uint2*>(&Ps[pbase]) = pw;
        }
        bf16x8 pa = *reinterpret_cast<const bf16x8*>(&Ps[w * 512 + l * 8]);
        __builtin_amdgcn_s_setprio(1);
        #pragma unroll
        for (int vt = 0; vt < 16; ++vt) {
          bf16x8 vb = *reinterpret_cast<const bf16x8*>(&Vs[cur][ks * 8192 + vt * 512 + l * 8]);
          acc[vt] = __builtin_amdgcn_mfma_f32_16x16x32_bf16(vb, pa, acc[vt], 0, 0, 0);
        }
        __builtin_amdgcn_s_setprio(0);
      }
    }
    __syncthreads();   // all readers of buf cur done (next iter stages into it)
    cur ^= 1;
  }
#undef ATTN_STAGE

  const float inv = 1.f / lsum;
  const int lrow = w * 16 + c;
  if (!issplit) {
    const int row = T * 128 + lrow;
    unsigned short* orow = outp + (size_t)row * 5120 + h * 256 + g * 4;
    #pragma unroll
    for (int vt = 0; vt < 16; ++vt) {
      uint2 o;
      o.x = pk2(acc[vt][0] * inv, acc[vt][1] * inv);
      o.y = pk2(acc[vt][2] * inv, acc[vt][3] * inv);
      *reinterpret_cast<uint2*>(orow + vt * 16) = o;
    }
  } else {
    const int pidx = ((T - 8) * 20 + h) * 2 + chunk;
    unsigned short* po = part_O + (size_t)pidx * 32768 + lrow * 256 + g * 4;
    #pragma unroll
    for (int vt = 0; vt < 16; ++vt) {
      uint2 o;
      o.x = pk2(acc[vt][0] * inv, acc[vt][1] * inv);
      o.y = pk2(acc[vt][2] * inv, acc[vt][3] * inv);
      *reinterpret_cast<uint2*>(po + vt * 16) = o;
    }
    if (g == 0)
      *reinterpret_cast<float2*>(&part_ml[(size_t)(pidx * 128 + lrow) * 2]) =
          make_float2(m, lsum);
  }
}

// ---------------- flash-combine merge for split tasks (128 rows) ------------
__global__ __launch_bounds__(256) void attn_merge_kernel(
    const unsigned short* __restrict__ part_O, const float* __restrict__ part_ml,
    unsigned short* __restrict__ outp) {
  const int b = blockIdx.x;        // 0..159: T = 8 + b/20, h = b%20
  const int T = 8 + b / 20;
  const int h = b % 20;
  const int t = threadIdx.x;
  const int lr = t >> 1;           // local row 0..127
  const int c0 = (t & 1) * 128;    // col base
  const int p0 = ((T - 8) * 20 + h) * 2;
  float m1 = part_ml[(size_t)(p0 * 128 + lr) * 2];
  float l1 = part_ml[(size_t)(p0 * 128 + lr) * 2 + 1];
  float m2 = part_ml[(size_t)((p0 + 1) * 128 + lr) * 2];
  float l2 = part_ml[(size_t)((p0 + 1) * 128 + lr) * 2 + 1];
  float M = fmaxf(m1, m2);
  float w1 = __expf(m1 - M) * l1, w2 = __expf(m2 - M) * l2;
  float inv = 1.f / (w1 + w2);
  w1 *= inv; w2 *= inv;
  const unsigned short* o1 = part_O + (size_t)p0 * 32768 + lr * 256 + c0;
  const unsigned short* o2 = part_O + (size_t)(p0 + 1) * 32768 + lr * 256 + c0;
  unsigned short* dst = outp + (size_t)(T * 128 + lr) * 5120 + h * 256 + c0;
  for (int j = 0; j < 128; j += 8) {
    bf16x8 a = *reinterpret_cast<const bf16x8*>(o1 + j);
    bf16x8 bb = *reinterpret_cast<const bf16x8*>(o2 + j);
    union { unsigned short u[8]; uint4 v; } o;
    #pragma unroll
    for (int e = 0; e < 8; ++e)
      o.u[e] = f2bf(w1 * bf2f((unsigned short)a[e]) + w2 * bf2f((unsigned short)bb[e]));
    *reinterpret_cast<uint4*>(dst + j) = o.v;
  }
}

extern "C" void kernel_launch(void* const* d_in, const int* in_sizes, int n_in,
                              void* d_out, int out_size, void* d_ws, size_t ws_size,
                              hipStream_t stream) {
  const float* hidden = (const float*)d_in[0];
  const float* w_q_a  = (const float*)d_in[1];
  const float* w_q_b  = (const float*)d_in[2];
  const float* w_kv_a = (const float*)d_in[3];
  const float* w_kv_b = (const float*)d_in[4];
  const float* w_o    = (const float*)d_in[5];
  const float* g_q_a  = (const float*)d_in[6];
  const float* g_kv_a = (const float*)d_in[7];
  float* out = (float*)d_out;

  const int S = 2048;
  char* ws = (char*)d_ws;
  // overlay plan; peak ~143 MB
  unsigned short* wo_t     = (unsigned short*)(ws + 0);          // [2048,5120] bf16
  unsigned short* wcat     = (unsigned short*)(ws + 20971520);   // [1344,2048] bf16
  unsigned short* wqb_t    = (unsigned short*)(ws + 26476544);   // [5120,768]
  unsigned short* wkvb_t   = (unsigned short*)(ws + 34340864);   // [8960,512]
  unsigned short* hid_bf   = (unsigned short*)(ws + 43515904);   // [2048,2048]
  float*          a_part   = (float*)(ws + 52428800);            // 22MB (S2 only)
  unsigned short* Qc       = (unsigned short*)(ws + 52428800);   // 21MB (S3+)
  unsigned short* Kc       = (unsigned short*)(ws + 73400320);   // 21MB
  unsigned short* Vc       = (unsigned short*)(ws + 94371840);   // 21MB
  unsigned short* q_c      = (unsigned short*)(ws + 115343360);  // [2048,768] bf16
  unsigned short* kv_c     = (unsigned short*)(ws + 118489088);  // [2048,512] bf16
  float*          ckv_rope = (float*)(ws + 120586240);           // [2048,64] f32
  float2*         rope_cs  = (float2*)(ws + 121110528);          // [2048,32] float2
  unsigned short* attn_bf  = (unsigned short*)(ws + 121634816);  // [2048,5120] bf16
  // S4 overlays (wqb_t/wkvb_t/hid_bf dead by attention time):
  unsigned short* part_O   = (unsigned short*)(ws + 26476544);   // 320 x 64KB = 21MB
  float*          part_ml  = (float*)(ws + 47448064);            // 320 x 1KB
  float*          wo_part  = (float*)(ws + 26476544);            // 33.5MB (S5 only)

  dim3 blk(256);
  dim3 tblk(32, 8);

  // S1: conversions / transposes / tables
  f32_to_bf16_kernel<<<2048, blk, 0, stream>>>(hidden, hid_bf, S * 2048 / 8);
  transpose_f32_bf16<<<dim3(768 / 32, 2048 / 32), tblk, 0, stream>>>(w_q_a, wcat, 2048, 768);
  transpose_f32_bf16<<<dim3(576 / 32, 2048 / 32), tblk, 0, stream>>>(
      w_kv_a, wcat + (size_t)768 * 2048, 2048, 576);
  transpose_f32_bf16<<<dim3(5120 / 32, 768 / 32), tblk, 0, stream>>>(w_q_b, wqb_t, 768, 5120);
  transpose_f32_bf16<<<dim3(8960 / 32, 512 / 32), tblk, 0, stream>>>(w_kv_b, wkvb_t, 512, 8960);
  transpose_f32_bf16<<<dim3(2048 / 32, 5120 / 32), tblk, 0, stream>>>(w_o, wo_t, 5120, 2048);
  rope_table_kernel<<<256, blk, 0, stream>>>(rope_cs);

  // S2: merged a-projection (N=1344, split-K 2) + norms
  gemm_mfma<0><<<dim3(11, 16, 2), blk, 0, stream>>>(
      hid_bf, wcat, a_part, nullptr, nullptr, S, 1344, 2048, 1024);
  rmsnormq_kernel<<<S, blk, 0, stream>>>(a_part, g_q_a, q_c, 1344, (size_t)S * 1344);
  kv_post_kernel<<<S, blk, 0, stream>>>(a_part, g_kv_a, kv_c, ckv_rope, 1344, (size_t)S * 1344);

  // S3: b-projections with fused pack epilogues
  gemm_mfma<2><<<dim3(40, 16, 1), blk, 0, stream>>>(
      q_c, wqb_t, Qc, nullptr, rope_cs, S, 5120, 768, 768);
  gemm_mfma<3><<<dim3(70, 16, 1), blk, 0, stream>>>(
      kv_c, wkvb_t, Kc, Vc, nullptr, S, 8960, 512, 512);
  krope_kernel<<<dim3(64, NHEADS), blk, 0, stream>>>(ckv_rope, rope_cs, Kc);

  // S4: attention (480 static blocks of 512 threads, QBLK=128, dbuf) + merge
  attn_mfma<<<480, dim3(512), 0, stream>>>(Qc, Kc, Vc, attn_bf, part_O, part_ml);
  attn_merge_kernel<<<160, blk, 0, stream>>>(part_O, part_ml, attn_bf);

  // S5: output projection (BK=64, split-K 2) + reduce
  gemm_wo<<<dim3(16, 16, 2), blk, 0, stream>>>(
      attn_bf, wo_t, wo_part, S, 2048, 5120, 2560);
  reduce_add_kernel<<<(S * 2048 / 4 + 255) / 256, blk, 0, stream>>>(
      wo_part, out, S * 2048 / 4, 2, (size_t)S * 2048 / 4);
}